// Round 7
// baseline (982.261 us; speedup 1.0000x reference)
//
#include <hip/hip_runtime.h>
#include <hip/hip_bf16.h>
#include <stdint.h>

// KVMemoryLayer: scores = x@keys^T (512x200000, K=1024 fp32), top-32/row,
// softmax, weighted gather of vals.
// R7: 8-wave shape (R6) + 2-deep register prefetch of A and B (R5's idea,
//     now fitting the 128-reg budget: acc32 + A16 + B32 + misc ~= 115).
//     Loads for K-steps t+1 AND t+2 stay in flight across the barrier, so
//     writeLDS's vmcnt wait is satisfied by ~1-step-old loads -> kills the
//     per-step HBM-latency stall that R4/R6 showed occupancy can't hide.

#define KTOP 32
#define MROWS 512
#define NKEYS 200000
#define DDIM 1024

#define BM 128
#define BN 128
#define BK 64
#define LDT 72          // padded LDS row length in bf16 elems (144 B)
#define NCOLT 1563      // ceil(200000/128)
#define NT 1568         // padded tile count (multiple of 8 for swizzle)
#define TCAP 256
#define CCAP 256
#define TMARGIN 0.125f  // >> 2*bf16-gemm error (~0.004); provable coverage

typedef __attribute__((ext_vector_type(4))) float f32x4;
typedef __attribute__((ext_vector_type(8))) short short8;

__device__ __forceinline__ unsigned short f2bf(float f) {      // hw RNE cvt
    __hip_bfloat16 h = __float2bfloat16(f);
    return *reinterpret_cast<unsigned short*>(&h);
}
__device__ __forceinline__ int enc16(unsigned short u) {       // monotone order-encode
    return (int)(u ^ ((u & 0x8000u) ? 0xFFFFu : 0x8000u));
}
__device__ __forceinline__ float dec_enc(int e) {              // encoded -> float
    unsigned short u = (unsigned short)((e & 0x8000) ? (e ^ 0x8000) : (e ^ 0xFFFF));
    return __uint_as_float((unsigned int)u << 16);
}
__device__ __forceinline__ float bf2f(unsigned short u) {
    return __uint_as_float((unsigned int)u << 16);
}

// ---------------------------------------------------------------- cvt x->bf16
__global__ void cvt_x_kernel(const float* __restrict__ x, unsigned short* __restrict__ xb) {
    int i = blockIdx.x * blockDim.x + threadIdx.x;      // 131072 threads, 4 elems each
    f32x4 v = reinterpret_cast<const f32x4*>(x)[i];
    ushort4 o;
    o.x = f2bf(v.x); o.y = f2bf(v.y); o.z = f2bf(v.z); o.w = f2bf(v.w);
    reinterpret_cast<ushort4*>(xb)[i] = o;
}

// ---------------------------------------------------------------- K1: scores
// 512 threads, 8 waves, wave grid 2 (rows) x 4 (cols); per wave 64x32 of C.
// 2-deep staging pipeline: sets 0/1 alternate; loads for t+1 and t+2 in flight.
__global__ __launch_bounds__(512, 4)
void score_gemm(const float* __restrict__ keys, const unsigned short* __restrict__ xb,
                unsigned short* __restrict__ scores, unsigned short* __restrict__ tilemax) {
    __shared__ unsigned short As[BM * LDT];
    __shared__ unsigned short Bs[BN * LDT];
    __shared__ int tmax[BM];

    const int tid  = threadIdx.x;
    const int lane = tid & 63;
    const int wid  = tid >> 6;          // 0..7
    const int wr   = wid >> 2;          // 0..1  (64-row slice)
    const int wc   = wid & 3;           // 0..3  (32-col slice)

    // XCD-group swizzle: the 4 row-tile blocks of one col-tile get bids that
    // are congruent mod 8 (same XCD under round-robin) and 8 apart (adjacent
    // in time). bid = ((p*4 + rt)*8 + s), g = p*8 + s.
    const int bid = blockIdx.x;
    const int s   = bid & 7;
    const int u   = bid >> 3;
    const int rt  = u & 3;
    const int g   = (u >> 2) * 8 + s;   // col tile 0..1567
    if (g >= NCOLT) return;
    const int row0 = rt * BM;
    const int col0 = g * BN;

    if (tid < BM) tmax[tid] = 0;        // enc 0 < any real finite score's enc

    f32x4 acc[4][2];                    // 32 regs/lane
#pragma unroll
    for (int m = 0; m < 4; m++)
#pragma unroll
        for (int n = 0; n < 2; n++) acc[m][n] = (f32x4){0.f, 0.f, 0.f, 0.f};

    // two independent staging reg sets -> loads for t+1 AND t+2 in flight
    short8 areg0[2], areg1[2];          // 8+8 regs
    f32x4  breg0[4], breg1[4];          // 16+16 regs

#define LOAD_A(ar, k0)                                                                  \
    _Pragma("unroll")                                                                   \
    for (int i = 0; i < 2; i++) {                                                       \
        int c = i * 512 + tid;                                                          \
        int r = c >> 3, j = c & 7;                                                      \
        ar[i] = *reinterpret_cast<const short8*>(xb + (size_t)(row0 + r) * DDIM + (k0) + j * 8); \
    }
#define LOAD_B(br, k0)                                                                  \
    _Pragma("unroll")                                                                   \
    for (int i = 0; i < 4; i++) {                                                       \
        int c = i * 512 + tid;                                                          \
        int r = c >> 4, j = c & 15;                                                     \
        int gr = col0 + r; gr = (gr < NKEYS) ? gr : (NKEYS - 1);                        \
        br[i] = *reinterpret_cast<const f32x4*>(keys + (size_t)gr * DDIM + (k0) + j * 4); \
    }
#define WRITE_LDS(ar, br)                                                               \
    _Pragma("unroll")                                                                   \
    for (int i = 0; i < 2; i++) {                                                       \
        int c = i * 512 + tid;                                                          \
        int r = c >> 3, j = c & 7;                                                      \
        *reinterpret_cast<short8*>(&As[r * LDT + j * 8]) = ar[i];                       \
    }                                                                                   \
    _Pragma("unroll")                                                                   \
    for (int i = 0; i < 4; i++) {                                                       \
        int c = i * 512 + tid;                                                          \
        int r = c >> 4, j = c & 15;                                                     \
        ushort4 o;                                                                      \
        o.x = f2bf(br[i].x); o.y = f2bf(br[i].y);                                       \
        o.z = f2bf(br[i].z); o.w = f2bf(br[i].w);                                       \
        *reinterpret_cast<ushort4*>(&Bs[r * LDT + j * 4]) = o;                          \
    }

    const int rl = lane & 15;
    const int kl = (lane >> 4) * 8;

    auto compute = [&]() {
        const unsigned short* Ab = &As[(wr * 64 + rl) * LDT + kl];
        const unsigned short* Bb = &Bs[(wc * 32 + rl) * LDT + kl];
#pragma unroll
        for (int kk = 0; kk < BK; kk += 32) {
            short8 af[4], bf[2];
#pragma unroll
            for (int m = 0; m < 4; m++) af[m] = *reinterpret_cast<const short8*>(Ab + m * 16 * LDT + kk);
#pragma unroll
            for (int n = 0; n < 2; n++) bf[n] = *reinterpret_cast<const short8*>(Bb + n * 16 * LDT + kk);
#pragma unroll
            for (int m = 0; m < 4; m++)
#pragma unroll
                for (int n = 0; n < 2; n++)
                    acc[m][n] = __builtin_amdgcn_mfma_f32_16x16x32_bf16(af[m], bf[n], acc[m][n], 0, 0, 0);
        }
    };

    // prologue: prefetch K-steps 0 (set0) and 1 (set1)
    LOAD_A(areg0, 0) LOAD_B(breg0, 0)
    LOAD_A(areg1, BK) LOAD_B(breg1, BK)

    for (int t = 0; t < DDIM / BK; t += 2) {
        // even step: consume set0; refill set0 with step t+2
        __syncthreads();
        WRITE_LDS(areg0, breg0)          // waits only on set0 (set1 stays in flight)
        __syncthreads();
        if (t + 2 < DDIM / BK) { LOAD_A(areg0, (t + 2) * BK) LOAD_B(breg0, (t + 2) * BK) }
        compute();
        // odd step: consume set1; refill set1 with step t+3
        __syncthreads();
        WRITE_LDS(areg1, breg1)
        __syncthreads();
        if (t + 3 < DDIM / BK) { LOAD_A(areg1, (t + 3) * BK) LOAD_B(breg1, (t + 3) * BK) }
        compute();
    }

    // epilogue: store bf16 scores (predicated) + per-(row,tile) max
    const int rg = lane >> 4;
#pragma unroll
    for (int m = 0; m < 4; m++) {
#pragma unroll
        for (int j = 0; j < 4; j++) {
            int lrow = wr * 64 + m * 16 + rg * 4 + j;
            int grow = row0 + lrow;
            float mx = -1e30f;
#pragma unroll
            for (int n = 0; n < 2; n++) {
                float v = acc[m][n][j];
                mx = fmaxf(mx, v);      // OOB lanes duplicate key NKEYS-1 (valid, in-tile)
                int gcol = col0 + wc * 32 + n * 16 + rl;
                if (gcol < NKEYS)
                    scores[(size_t)grow * NKEYS + gcol] = f2bf(v);
            }
#pragma unroll
            for (int sft = 1; sft < 16; sft <<= 1) mx = fmaxf(mx, __shfl_xor(mx, sft));
            if (rl == 0)
                atomicMax(&tmax[lrow], enc16(f2bf(mx)));
        }
    }
    __syncthreads();
    if (tid < BM)
        tilemax[(size_t)(row0 + tid) * NT + g] = (unsigned short)tmax[tid];
}

// ------------------------------------------------- K2: select+refine+output
__global__ __launch_bounds__(256)
void select_kernel(const float* __restrict__ x, const float* __restrict__ keys,
                   const float* __restrict__ vals, const unsigned short* __restrict__ scores,
                   const unsigned short* __restrict__ tilemax, float* __restrict__ out) {
    const int n    = blockIdx.x;
    const int tid  = threadIdx.x;
    const int lane = tid & 63;
    const int w    = tid >> 6;

    __shared__ __align__(16) float qs[DDIM];
    __shared__ unsigned short enc_t[NT];
    __shared__ int    hist[256];
    __shared__ int    tiles[TCAP];
    __shared__ int    cand[CCAP];
    __shared__ double rsc[CCAP];
    __shared__ float  wgt[KTOP];
    __shared__ int    topslot[KTOP];
    __shared__ float  topval[KTOP];
    __shared__ int    ntiles, ncand, sbsel, sabove, st32e;

    reinterpret_cast<f32x4*>(qs)[tid] = reinterpret_cast<const f32x4*>(x + (size_t)n * DDIM)[tid];
    hist[tid] = 0;
    if (tid < 32) { wgt[tid] = 0.f; topslot[tid] = -1; }
    if (tid == 0) { ntiles = 0; ncand = 0; }
    // load tile-max row (encoded bf16); phantom tiles (>=NCOLT) forced to 0
    for (int i = tid; i < NT; i += 256)
        enc_t[i] = (i < NCOLT) ? tilemax[(size_t)n * NT + i] : 0;
    __syncthreads();

    // --- exact 32nd-largest tile-max via two-level 8-bit radix ---
    for (int i = tid; i < NT; i += 256) atomicAdd(&hist[enc_t[i] >> 8], 1);
    __syncthreads();
    if (tid == 0) {
        int cum = 0, b = 255;
        for (; b >= 0; b--) { cum += hist[b]; if (cum >= KTOP) break; }
        sbsel = b; sabove = cum - hist[b];
    }
    __syncthreads();
    const int bsel = sbsel;
    hist[tid] = 0;
    __syncthreads();
    for (int i = tid; i < NT; i += 256) {
        int e = enc_t[i];
        if ((e >> 8) == bsel) atomicAdd(&hist[e & 0xFF], 1);
    }
    __syncthreads();
    if (tid == 0) {
        int cum = sabove, lb = 255;
        for (; lb >= 0; lb--) { cum += hist[lb]; if (cum >= KTOP) break; }
        st32e = (bsel << 8) | lb;
    }
    __syncthreads();
    const float thr = dec_enc(st32e) - TMARGIN;   // covers exact top-32 (margin >> 2*delta)

    // --- select tiles with max >= thr ---
    for (int i = tid; i < NT; i += 256) {
        if (dec_enc(enc_t[i]) >= thr) {
            int p = atomicAdd(&ntiles, 1);
            if (p < TCAP) tiles[p] = i;
        }
    }
    __syncthreads();
    const int nt = ntiles < TCAP ? ntiles : TCAP;

    // --- scan selected tiles, collect candidates >= thr ---
    for (int idx = tid; idx < nt * BN; idx += 256) {
        int col = tiles[idx >> 7] * BN + (idx & 127);
        if (col < NKEYS) {
            float v = bf2f(scores[(size_t)n * NKEYS + col]);
            if (v >= thr) {
                int p = atomicAdd(&ncand, 1);
                if (p < CCAP) cand[p] = col;
            }
        }
    }
    __syncthreads();
    const int cnt = ncand < CCAP ? ncand : CCAP;

    // --- refine: exact dot(x_row, keys[cand]) with f64 accum, one wave/cand ---
    for (int ci = w; ci < cnt; ci += 4) {
        const f32x4* kv = reinterpret_cast<const f32x4*>(keys + (size_t)cand[ci] * DDIM) + lane * 4;
        const f32x4* qv = reinterpret_cast<const f32x4*>(qs) + lane * 4;
        double a = 0.0;
#pragma unroll
        for (int i = 0; i < 4; i++) {
            f32x4 q = qv[i], k = kv[i];
            a += (double)q.x * k.x + (double)q.y * k.y + (double)q.z * k.z + (double)q.w * k.w;
        }
#pragma unroll
        for (int sft = 32; sft >= 1; sft >>= 1) a += __shfl_xor(a, sft);
        if (lane == 0) rsc[ci] = a;
    }
    __syncthreads();

    // --- exact top-32 among candidates (wave 0, 4 slots covers CCAP=256) ---
    if (w == 0) {
        double v0[4]; int id0[4];
#pragma unroll
        for (int sft = 0; sft < 4; sft++) {
            int p = lane + sft * 64;
            if (p < cnt) { v0[sft] = rsc[p]; id0[sft] = p; } else { v0[sft] = -1e300; id0[sft] = -1; }
        }
        for (int k = 0; k < KTOP; k++) {
            double bv = v0[0]; int bi = id0[0];
#pragma unroll
            for (int sft = 1; sft < 4; sft++) if (v0[sft] > bv) { bv = v0[sft]; bi = id0[sft]; }
#pragma unroll
            for (int sft = 32; sft >= 1; sft >>= 1) {
                double ov = __shfl_xor(bv, sft);
                int    oi = __shfl_xor(bi, sft);
                if (ov > bv) { bv = ov; bi = oi; }
            }
            if (lane == 0) { topslot[k] = bi; topval[k] = (float)bv; }
#pragma unroll
            for (int sft = 0; sft < 4; sft++) if (bi >= 0 && id0[sft] == bi) v0[sft] = -1e300;
        }
    }
    __syncthreads();

    // --- softmax over the 32 exact scores ---
    if (tid == 0) {
        float mx = topval[0];
        float sum = 0.f;
        for (int k = 0; k < KTOP; k++) {
            float e = (topslot[k] >= 0) ? expf(topval[k] - mx) : 0.f;
            wgt[k] = e; sum += e;
        }
        float inv = 1.f / sum;
        for (int k = 0; k < KTOP; k++) wgt[k] *= inv;
    }
    __syncthreads();

    // --- output: weighted sum of selected vals rows ---
    f32x4 accv = (f32x4){0.f, 0.f, 0.f, 0.f};
    for (int k = 0; k < KTOP; k++) {
        int sl = topslot[k];
        if (sl >= 0) {
            float wk = wgt[k];
            f32x4 v = reinterpret_cast<const f32x4*>(vals + (size_t)cand[sl] * DDIM)[tid];
            accv.x += wk * v.x; accv.y += wk * v.y; accv.z += wk * v.z; accv.w += wk * v.w;
        }
    }
    reinterpret_cast<f32x4*>(out + (size_t)n * DDIM)[tid] = accv;
}

// ---------------------------------------------------------------- launch
extern "C" void kernel_launch(void* const* d_in, const int* in_sizes, int n_in,
                              void* d_out, int out_size, void* d_ws, size_t ws_size,
                              hipStream_t stream) {
    const float* x    = (const float*)d_in[0];
    const float* keys = (const float*)d_in[1];
    const float* vals = (const float*)d_in[2];
    float* out = (float*)d_out;

    char* ws = (char*)d_ws;
    unsigned short* scores  = (unsigned short*)ws;                         // 204,800,000 B
    unsigned short* xb      = (unsigned short*)(ws + 204800000);           //   1,048,576 B
    unsigned short* tilemax = (unsigned short*)(ws + 204800000 + 1048576); //   1,605,632 B

    cvt_x_kernel<<<512, 256, 0, stream>>>(x, xb);
    score_gemm<<<4 * NT, 512, 0, stream>>>(keys, xb, scores, tilemax);
    select_kernel<<<MROWS, 256, 0, stream>>>(x, keys, vals, scores, tilemax, out);
}

// Round 8
// 881.225 us; speedup vs baseline: 1.1147x; 1.1147x over previous
//
#include <hip/hip_runtime.h>
#include <hip/hip_bf16.h>
#include <stdint.h>

// KVMemoryLayer: scores = x@keys^T (512x200000, K=1024 fp32), top-32/row,
// softmax, weighted gather of vals.
// R8: score_gemm restructured around global_load_lds (T3/T4):
//     - B staged as fp32 via global_load_lds, TRI-buffered, issued 2 tiles
//       ahead; counted s_waitcnt vmcnt(16) + raw s_barrier per K-step (never
//       drain to 0 in the loop). fp32->bf16 conversion moved to fragment
//       build (off the vmcnt critical path).
//     - A (bf16, L2-resident) reg-staged with 2 small sets, LDS dbuf,
//       proven LDT=72 padded layout.
//     - B LDS linear (gload_lds requires it) + XOR-preswizzled global source,
//       same XOR on read (rule #21) -> ~2-way bank conflicts.
//     Zero staging VGPRs for B => no spill (R5/R7 killer). LDS 132KB,
//     1 block/CU: pipeline depth replaces TLP.

#define KTOP 32
#define MROWS 512
#define NKEYS 200000
#define DDIM 1024

#define BM 128
#define BN 128
#define BK 64
#define LDT 72          // padded A row length in bf16 elems (144 B, 16B-aligned)
#define NSTEP 16        // DDIM/BK
#define NCOLT 1563      // ceil(200000/128)
#define NT 1568         // padded tile count (multiple of 8 for swizzle)
#define TCAP 256
#define CCAP 256
#define TMARGIN 0.125f  // >> 2*bf16-gemm error (~0.004); provable coverage

typedef __attribute__((ext_vector_type(4))) float f32x4;
typedef __attribute__((ext_vector_type(8))) short short8;

__device__ __forceinline__ unsigned short f2bf(float f) {      // hw RNE cvt
    __hip_bfloat16 h = __float2bfloat16(f);
    return *reinterpret_cast<unsigned short*>(&h);
}
__device__ __forceinline__ int enc16(unsigned short u) {       // monotone order-encode
    return (int)(u ^ ((u & 0x8000u) ? 0xFFFFu : 0x8000u));
}
__device__ __forceinline__ float dec_enc(int e) {              // encoded -> float
    unsigned short u = (unsigned short)((e & 0x8000) ? (e ^ 0x8000) : (e ^ 0xFFFF));
    return __uint_as_float((unsigned int)u << 16);
}
__device__ __forceinline__ float bf2f(unsigned short u) {
    return __uint_as_float((unsigned int)u << 16);
}

// ---------------------------------------------------------------- cvt x->bf16
__global__ void cvt_x_kernel(const float* __restrict__ x, unsigned short* __restrict__ xb) {
    int i = blockIdx.x * blockDim.x + threadIdx.x;      // 131072 threads, 4 elems each
    f32x4 v = reinterpret_cast<const f32x4*>(x)[i];
    ushort4 o;
    o.x = f2bf(v.x); o.y = f2bf(v.y); o.z = f2bf(v.z); o.w = f2bf(v.w);
    reinterpret_cast<ushort4*>(xb)[i] = o;
}

// ---------------------------------------------------------------- K1: scores
__global__ __launch_bounds__(256)
void score_gemm(const float* __restrict__ keys, const unsigned short* __restrict__ xb,
                unsigned short* __restrict__ scores, unsigned short* __restrict__ tilemax) {
    __shared__ __align__(16) unsigned short As[2][BM * LDT];   // 36 KB
    __shared__ __align__(16) float Bsf[3][BN * BK];            // 96 KB
    __shared__ int tmax[BM];

    const int tid  = threadIdx.x;
    const int lane = tid & 63;
    const int wid  = tid >> 6;
    const int wr   = wid >> 1;          // 2x2 wave grid, 64x64 per wave
    const int wc   = wid & 1;

    // XCD-group swizzle (R3-proven)
    const int bid = blockIdx.x;
    const int s   = bid & 7;
    const int u   = bid >> 3;
    const int rt  = u & 3;
    const int g   = (u >> 2) * 8 + s;   // col tile 0..1567
    if (g >= NCOLT) return;
    const int row0 = rt * BM;
    const int col0 = g * BN;

    if (tid < BM) tmax[tid] = 0;

    f32x4 acc[4][4];
#pragma unroll
    for (int m = 0; m < 4; m++)
#pragma unroll
        for (int n = 0; n < 4; n++) acc[m][n] = (f32x4){0.f, 0.f, 0.f, 0.f};

    short8 areg0[4], areg1[4];          // two A staging sets (parity-static)

    auto loadA = [&](short8 (&ar)[4], int t) {
        if (t >= NSTEP) return;
        const int k0 = t * BK;
#pragma unroll
        for (int i = 0; i < 4; i++) {
            int c = i * 256 + tid;
            int r = c >> 3, j = c & 7;
            ar[i] = *reinterpret_cast<const short8*>(xb + (size_t)(row0 + r) * DDIM + k0 + j * 8);
        }
    };
    auto writeA = [&](int asel, short8 (&ar)[4]) {
#pragma unroll
        for (int i = 0; i < 4; i++) {
            int c = i * 256 + tid;
            int r = c >> 3, j = c & 7;
            *reinterpret_cast<short8*>(&As[asel][r * LDT + j * 8]) = ar[i];
        }
    };
    // B: 8 x global_load_lds(16B) per thread per tile. LDS dest LINEAR
    // (slot cb=i*256+tid -> lane-contiguous per wave); global source chunk
    // index XOR-preswizzled: LDS slot (r,jc) holds global chunk (r, jc^(r&7)).
    auto issueB = [&](int t) {
        if (t >= NSTEP) return;
        const int bsel = t % 3;
        const size_t kbyte = (size_t)t * 256;
        char* ldsbase = (char*)&Bsf[bsel][0];
#pragma unroll
        for (int i = 0; i < 8; i++) {
            int cb = i * 256 + tid;
            int r = cb >> 4, jc = cb & 15;
            int js = jc ^ (r & 7);
            int gr = col0 + r; gr = (gr < NKEYS) ? gr : (NKEYS - 1);   // clamp OOB
            const char* src = (const char*)keys + (size_t)gr * 4096 + kbyte + (size_t)js * 16;
            __builtin_amdgcn_global_load_lds(
                (const __attribute__((address_space(1))) unsigned int*)src,
                (__attribute__((address_space(3))) unsigned int*)(ldsbase + (size_t)cb * 16),
                16, 0, 0);
        }
    };

    const int rl = lane & 15;
    const int kl = (lane >> 4) * 8;

    auto compute = [&](int asel, int bsel) {
        const unsigned short* Ab = &As[asel][(wr * 64 + rl) * LDT + kl];
        const float* Bf = &Bsf[bsel][0];
        const int rB0 = wc * 64 + rl;
#pragma unroll
        for (int kk = 0; kk < BK; kk += 32) {
            short8 af[4], bf[4];
#pragma unroll
            for (int m = 0; m < 4; m++) af[m] = *reinterpret_cast<const short8*>(Ab + m * 16 * LDT + kk);
#pragma unroll
            for (int n = 0; n < 4; n++) {
                int row = rB0 + n * 16;
                int sw  = row & 7;
                int jc0 = (kk + kl) >> 2;                       // even; frag = chunks jc0, jc0+1
                f32x4 c0 = *reinterpret_cast<const f32x4*>(Bf + row * 64 + ((jc0 ^ sw) << 2));
                f32x4 c1 = *reinterpret_cast<const f32x4*>(Bf + row * 64 + (((jc0 + 1) ^ sw) << 2));
                short8 b;
                b[0] = (short)f2bf(c0.x); b[1] = (short)f2bf(c0.y);
                b[2] = (short)f2bf(c0.z); b[3] = (short)f2bf(c0.w);
                b[4] = (short)f2bf(c1.x); b[5] = (short)f2bf(c1.y);
                b[6] = (short)f2bf(c1.z); b[7] = (short)f2bf(c1.w);
                bf[n] = b;
            }
#pragma unroll
            for (int m = 0; m < 4; m++)
#pragma unroll
                for (int n = 0; n < 4; n++)
                    acc[m][n] = __builtin_amdgcn_mfma_f32_16x16x32_bf16(af[m], bf[n], acc[m][n], 0, 0, 0);
        }
    };

    // counted-vmcnt sync: never drain B prefetches in the main loop
#define SYNC(N) do { asm volatile("s_waitcnt vmcnt(" #N ")" ::: "memory");  \
                     asm volatile("s_waitcnt lgkmcnt(0)" ::: "memory");     \
                     __builtin_amdgcn_sched_barrier(0);                     \
                     __builtin_amdgcn_s_barrier();                          \
                     __builtin_amdgcn_sched_barrier(0); } while (0)

    // ---- prologue: A(0)->LDS0, A(1)/A(2) in regs, B(0)/B(1) in flight
    loadA(areg0, 0);
    issueB(0); issueB(1);
    loadA(areg1, 1);
    writeA(0, areg0);        // compiler waits only A(0) (B stays in flight)
    loadA(areg0, 2);
    SYNC(16);                // residual = B(1)8 + A(1)4 + A(2)4 -> B(0) arrived

    // ---- main loop; steady residual = B(t+2)8 + A(t+2)4 + A(t+3)4 = 16
    for (int t = 0; t < 12; t += 2) {
        issueB(t + 2); writeA(1, areg1); loadA(areg1, t + 3);
        compute(0, t % 3);
        SYNC(16);
        issueB(t + 3); writeA(0, areg0); loadA(areg0, t + 4);
        compute(1, (t + 1) % 3);
        SYNC(16);
    }
    // t = 12
    issueB(14); writeA(1, areg1); loadA(areg1, 15);
    compute(0, 0);
    SYNC(16);
    // t = 13
    issueB(15); writeA(0, areg0);
    compute(1, 1);
    SYNC(12);                // residual = B(15)8 + A(15)4
    // t = 14
    writeA(1, areg1);
    compute(0, 2);
    SYNC(0);
    // t = 15
    compute(1, 0);

    // ---- epilogue: store bf16 scores (predicated) + per-(row,tile) max
    const int rg = lane >> 4;
#pragma unroll
    for (int m = 0; m < 4; m++) {
#pragma unroll
        for (int j = 0; j < 4; j++) {
            int lrow = wr * 64 + m * 16 + rg * 4 + j;
            int grow = row0 + lrow;
            float mx = -1e30f;
#pragma unroll
            for (int n = 0; n < 4; n++) {
                float v = acc[m][n][j];
                mx = fmaxf(mx, v);
                int gcol = col0 + wc * 64 + n * 16 + rl;
                if (gcol < NKEYS)
                    scores[(size_t)grow * NKEYS + gcol] = f2bf(v);
            }
#pragma unroll
            for (int sft = 1; sft < 16; sft <<= 1) mx = fmaxf(mx, __shfl_xor(mx, sft));
            if (rl == 0)
                atomicMax(&tmax[lrow], enc16(f2bf(mx)));
        }
    }
    __syncthreads();
    if (tid < BM)
        tilemax[(size_t)(row0 + tid) * NT + g] = (unsigned short)tmax[tid];
#undef SYNC
}

// ------------------------------------------------- K2: select+refine+output
__global__ __launch_bounds__(256)
void select_kernel(const float* __restrict__ x, const float* __restrict__ keys,
                   const float* __restrict__ vals, const unsigned short* __restrict__ scores,
                   const unsigned short* __restrict__ tilemax, float* __restrict__ out) {
    const int n    = blockIdx.x;
    const int tid  = threadIdx.x;
    const int lane = tid & 63;
    const int w    = tid >> 6;

    __shared__ __align__(16) float qs[DDIM];
    __shared__ unsigned short enc_t[NT];
    __shared__ int    hist[256];
    __shared__ int    tiles[TCAP];
    __shared__ int    cand[CCAP];
    __shared__ double rsc[CCAP];
    __shared__ float  wgt[KTOP];
    __shared__ int    topslot[KTOP];
    __shared__ float  topval[KTOP];
    __shared__ int    ntiles, ncand, sbsel, sabove, st32e;

    reinterpret_cast<f32x4*>(qs)[tid] = reinterpret_cast<const f32x4*>(x + (size_t)n * DDIM)[tid];
    hist[tid] = 0;
    if (tid < 32) { wgt[tid] = 0.f; topslot[tid] = -1; }
    if (tid == 0) { ntiles = 0; ncand = 0; }
    for (int i = tid; i < NT; i += 256)
        enc_t[i] = (i < NCOLT) ? tilemax[(size_t)n * NT + i] : 0;
    __syncthreads();

    // --- exact 32nd-largest tile-max via two-level 8-bit radix ---
    for (int i = tid; i < NT; i += 256) atomicAdd(&hist[enc_t[i] >> 8], 1);
    __syncthreads();
    if (tid == 0) {
        int cum = 0, b = 255;
        for (; b >= 0; b--) { cum += hist[b]; if (cum >= KTOP) break; }
        sbsel = b; sabove = cum - hist[b];
    }
    __syncthreads();
    const int bsel = sbsel;
    hist[tid] = 0;
    __syncthreads();
    for (int i = tid; i < NT; i += 256) {
        int e = enc_t[i];
        if ((e >> 8) == bsel) atomicAdd(&hist[e & 0xFF], 1);
    }
    __syncthreads();
    if (tid == 0) {
        int cum = sabove, lb = 255;
        for (; lb >= 0; lb--) { cum += hist[lb]; if (cum >= KTOP) break; }
        st32e = (bsel << 8) | lb;
    }
    __syncthreads();
    const float thr = dec_enc(st32e) - TMARGIN;

    // --- select tiles with max >= thr ---
    for (int i = tid; i < NT; i += 256) {
        if (dec_enc(enc_t[i]) >= thr) {
            int p = atomicAdd(&ntiles, 1);
            if (p < TCAP) tiles[p] = i;
        }
    }
    __syncthreads();
    const int nt = ntiles < TCAP ? ntiles : TCAP;

    // --- scan selected tiles, collect candidates >= thr ---
    for (int idx = tid; idx < nt * BN; idx += 256) {
        int col = tiles[idx >> 7] * BN + (idx & 127);
        if (col < NKEYS) {
            float v = bf2f(scores[(size_t)n * NKEYS + col]);
            if (v >= thr) {
                int p = atomicAdd(&ncand, 1);
                if (p < CCAP) cand[p] = col;
            }
        }
    }
    __syncthreads();
    const int cnt = ncand < CCAP ? ncand : CCAP;

    // --- refine: exact dot(x_row, keys[cand]) with f64 accum, one wave/cand ---
    for (int ci = w; ci < cnt; ci += 4) {
        const f32x4* kv = reinterpret_cast<const f32x4*>(keys + (size_t)cand[ci] * DDIM) + lane * 4;
        const f32x4* qv = reinterpret_cast<const f32x4*>(qs) + lane * 4;
        double a = 0.0;
#pragma unroll
        for (int i = 0; i < 4; i++) {
            f32x4 q = qv[i], k = kv[i];
            a += (double)q.x * k.x + (double)q.y * k.y + (double)q.z * k.z + (double)q.w * k.w;
        }
#pragma unroll
        for (int sft = 32; sft >= 1; sft >>= 1) a += __shfl_xor(a, sft);
        if (lane == 0) rsc[ci] = a;
    }
    __syncthreads();

    // --- exact top-32 among candidates (wave 0) ---
    if (w == 0) {
        double v0[4]; int id0[4];
#pragma unroll
        for (int sft = 0; sft < 4; sft++) {
            int p = lane + sft * 64;
            if (p < cnt) { v0[sft] = rsc[p]; id0[sft] = p; } else { v0[sft] = -1e300; id0[sft] = -1; }
        }
        for (int k = 0; k < KTOP; k++) {
            double bv = v0[0]; int bi = id0[0];
#pragma unroll
            for (int sft = 1; sft < 4; sft++) if (v0[sft] > bv) { bv = v0[sft]; bi = id0[sft]; }
#pragma unroll
            for (int sft = 32; sft >= 1; sft >>= 1) {
                double ov = __shfl_xor(bv, sft);
                int    oi = __shfl_xor(bi, sft);
                if (ov > bv) { bv = ov; bi = oi; }
            }
            if (lane == 0) { topslot[k] = bi; topval[k] = (float)bv; }
#pragma unroll
            for (int sft = 0; sft < 4; sft++) if (bi >= 0 && id0[sft] == bi) v0[sft] = -1e300;
        }
    }
    __syncthreads();

    // --- softmax over the 32 exact scores ---
    if (tid == 0) {
        float mx = topval[0];
        float sum = 0.f;
        for (int k = 0; k < KTOP; k++) {
            float e = (topslot[k] >= 0) ? expf(topval[k] - mx) : 0.f;
            wgt[k] = e; sum += e;
        }
        float inv = 1.f / sum;
        for (int k = 0; k < KTOP; k++) wgt[k] *= inv;
    }
    __syncthreads();

    // --- output: weighted sum of selected vals rows ---
    f32x4 accv = (f32x4){0.f, 0.f, 0.f, 0.f};
    for (int k = 0; k < KTOP; k++) {
        int sl = topslot[k];
        if (sl >= 0) {
            float wk = wgt[k];
            f32x4 v = reinterpret_cast<const f32x4*>(vals + (size_t)cand[sl] * DDIM)[tid];
            accv.x += wk * v.x; accv.y += wk * v.y; accv.z += wk * v.z; accv.w += wk * v.w;
        }
    }
    reinterpret_cast<f32x4*>(out + (size_t)n * DDIM)[tid] = accv;
}

// ---------------------------------------------------------------- launch
extern "C" void kernel_launch(void* const* d_in, const int* in_sizes, int n_in,
                              void* d_out, int out_size, void* d_ws, size_t ws_size,
                              hipStream_t stream) {
    const float* x    = (const float*)d_in[0];
    const float* keys = (const float*)d_in[1];
    const float* vals = (const float*)d_in[2];
    float* out = (float*)d_out;

    char* ws = (char*)d_ws;
    unsigned short* scores  = (unsigned short*)ws;                         // 204,800,000 B
    unsigned short* xb      = (unsigned short*)(ws + 204800000);           //   1,048,576 B
    unsigned short* tilemax = (unsigned short*)(ws + 204800000 + 1048576); //   1,605,632 B

    cvt_x_kernel<<<512, 256, 0, stream>>>(x, xb);
    score_gemm<<<4 * NT, 256, 0, stream>>>(keys, xb, scores, tilemax);
    select_kernel<<<MROWS, 256, 0, stream>>>(x, keys, vals, scores, tilemax, out);
}

// Round 9
// 661.627 us; speedup vs baseline: 1.4846x; 1.3319x over previous
//
#include <hip/hip_runtime.h>
#include <hip/hip_bf16.h>
#include <stdint.h>

// KVMemoryLayer: scores = x@keys^T (512x200000, K=1024 fp32), top-32/row,
// softmax, weighted gather of vals.
// R9: m97-clone staging: ALL staging via global_load_lds (zero staging VGPRs
//     -> no spill, the R5/R7/R8 killer). BK=32 so fp32-B dbuf fits: LDS
//     48.5KB -> 3 blocks/CU. ONE plain __syncthreads per K-step (compiler's
//     proven drain; no inline asm). B stored fp32 in LDS (gload_lds can't
//     convert), converted to bf16 at fragment build (8 cvt/lane/frag).
//     Bank conflicts killed by XOR pre-swizzle of the SOURCE chunk index +
//     same XOR on the read (rule #21): B ch^=(row&7), A ch^=((row>>1)&3).

#define KTOP 32
#define MROWS 512
#define NKEYS 200000
#define DDIM 1024

#define BM 128
#define BN 128
#define BK 32
#define NSTEP 32        // DDIM/BK
#define NCOLT 1563      // ceil(200000/128)
#define NT 1568         // padded tile count (multiple of 8 for swizzle)
#define TCAP 256
#define CCAP 256
#define TMARGIN 0.125f  // >> 2*bf16-gemm error (~0.004); provable coverage

typedef __attribute__((ext_vector_type(4))) float f32x4;
typedef __attribute__((ext_vector_type(8))) short short8;

__device__ __forceinline__ unsigned short f2bf(float f) {      // hw RNE cvt
    __hip_bfloat16 h = __float2bfloat16(f);
    return *reinterpret_cast<unsigned short*>(&h);
}
__device__ __forceinline__ int enc16(unsigned short u) {       // monotone order-encode
    return (int)(u ^ ((u & 0x8000u) ? 0xFFFFu : 0x8000u));
}
__device__ __forceinline__ float dec_enc(int e) {              // encoded -> float
    unsigned short u = (unsigned short)((e & 0x8000) ? (e ^ 0x8000) : (e ^ 0xFFFF));
    return __uint_as_float((unsigned int)u << 16);
}
__device__ __forceinline__ float bf2f(unsigned short u) {
    return __uint_as_float((unsigned int)u << 16);
}

// ---------------------------------------------------------------- cvt x->bf16
__global__ void cvt_x_kernel(const float* __restrict__ x, unsigned short* __restrict__ xb) {
    int i = blockIdx.x * blockDim.x + threadIdx.x;      // 131072 threads, 4 elems each
    f32x4 v = reinterpret_cast<const f32x4*>(x)[i];
    ushort4 o;
    o.x = f2bf(v.x); o.y = f2bf(v.y); o.z = f2bf(v.z); o.w = f2bf(v.w);
    reinterpret_cast<ushort4*>(xb)[i] = o;
}

// ---------------------------------------------------------------- K1: scores
__global__ __launch_bounds__(256, 3)
void score_gemm(const float* __restrict__ keys, const unsigned short* __restrict__ xb,
                unsigned short* __restrict__ scores, unsigned short* __restrict__ tilemax) {
    // A: [2][128 rows][32 bf16] linear (64 B/row = 4 chunks of 16B)
    // B: [2][128 rows][32 fp32] linear (128 B/row = 8 chunks of 16B)
    __shared__ __align__(16) unsigned short As[2][BM * BK];
    __shared__ __align__(16) float          Bs[2][BN * BK];
    __shared__ int tmax[BM];

    const int tid  = threadIdx.x;
    const int lane = tid & 63;
    const int wid  = tid >> 6;
    const int wr   = wid >> 1;          // 2x2 wave grid, 64x64 per wave
    const int wc   = wid & 1;

    // XCD-group swizzle (R3-proven)
    const int bid = blockIdx.x;
    const int s   = bid & 7;
    const int u   = bid >> 3;
    const int rt  = u & 3;
    const int g   = (u >> 2) * 8 + s;   // col tile 0..1567
    if (g >= NCOLT) return;
    const int row0 = rt * BM;
    const int col0 = g * BN;

    if (tid < BM) tmax[tid] = 0;

    f32x4 acc[4][4];
#pragma unroll
    for (int m = 0; m < 4; m++)
#pragma unroll
        for (int n = 0; n < 4; n++) acc[m][n] = (f32x4){0.f, 0.f, 0.f, 0.f};

    // Stage K-step t into buffer b. A: 2 chunks/thread, B: 4 chunks/thread.
    // LDS dest LINEAR; global source chunk XOR-preswizzled (read applies same XOR).
    auto issueAB = [&](int t, int b) {
        char* abase = (char*)&As[b][0];
        char* bbase = (char*)&Bs[b][0];
        // A: 512 chunks (128 rows x 4)
#pragma unroll
        for (int i = 0; i < 2; i++) {
            int ca = i * 256 + tid;
            int r = ca >> 2, jc = ca & 3;
            int js = jc ^ ((r >> 1) & 3);
            const char* src = (const char*)xb + (size_t)(row0 + r) * 2048 + (size_t)t * 64 + (size_t)js * 16;
            __builtin_amdgcn_global_load_lds(
                (const __attribute__((address_space(1))) unsigned int*)src,
                (__attribute__((address_space(3))) unsigned int*)(abase + (size_t)ca * 16),
                16, 0, 0);
        }
        // B: 1024 chunks (128 rows x 8)
#pragma unroll
        for (int i = 0; i < 4; i++) {
            int cb = i * 256 + tid;
            int r = cb >> 3, jc = cb & 7;
            int js = jc ^ (r & 7);
            int gr = col0 + r; gr = (gr < NKEYS) ? gr : (NKEYS - 1);   // clamp OOB
            const char* src = (const char*)keys + (size_t)gr * 4096 + (size_t)t * 128 + (size_t)js * 16;
            __builtin_amdgcn_global_load_lds(
                (const __attribute__((address_space(1))) unsigned int*)src,
                (__attribute__((address_space(3))) unsigned int*)(bbase + (size_t)cb * 16),
                16, 0, 0);
        }
    };

    const int rl = lane & 15;
    const int kg = lane >> 4;           // 0..3: k-group, 8 elems each

    auto compute = [&](int b) {
        const unsigned short* Ab = &As[b][0];
        const float* Bf = &Bs[b][0];
        short8 af[4], bf[4];
#pragma unroll
        for (int m = 0; m < 4; m++) {
            int ra = wr * 64 + m * 16 + rl;
            int ja = kg ^ ((ra >> 1) & 3);                 // A chunk XOR (matches source)
            af[m] = *reinterpret_cast<const short8*>(Ab + ra * 32 + ja * 8);
        }
#pragma unroll
        for (int n = 0; n < 4; n++) {
            int rb = wc * 64 + n * 16 + rl;
            int sw = rb & 7;
            int jc0 = kg * 2;                              // fp32 chunks: kg*2, kg*2+1
            f32x4 c0 = *reinterpret_cast<const f32x4*>(Bf + rb * 32 + ((jc0 ^ sw) << 2));
            f32x4 c1 = *reinterpret_cast<const f32x4*>(Bf + rb * 32 + (((jc0 + 1) ^ sw) << 2));
            short8 bq;
            bq[0] = (short)f2bf(c0.x); bq[1] = (short)f2bf(c0.y);
            bq[2] = (short)f2bf(c0.z); bq[3] = (short)f2bf(c0.w);
            bq[4] = (short)f2bf(c1.x); bq[5] = (short)f2bf(c1.y);
            bq[6] = (short)f2bf(c1.z); bq[7] = (short)f2bf(c1.w);
            bf[n] = bq;
        }
#pragma unroll
        for (int m = 0; m < 4; m++)
#pragma unroll
            for (int n = 0; n < 4; n++)
                acc[m][n] = __builtin_amdgcn_mfma_f32_16x16x32_bf16(af[m], bf[n], acc[m][n], 0, 0, 0);
    };

    // m97-style loop: 1 barrier per K-step; compiler drains vmcnt at barrier.
    issueAB(0, 0);
    for (int t = 0; t < NSTEP; t++) {
        __syncthreads();                         // buf[t&1] arrived; prev reads done
        if (t + 1 < NSTEP) issueAB(t + 1, (t + 1) & 1);
        compute(t & 1);
    }

    // epilogue: store bf16 scores (predicated) + per-(row,tile) max
    __syncthreads();                             // tmax init visible; computes done
    const int rg = lane >> 4;
#pragma unroll
    for (int m = 0; m < 4; m++) {
#pragma unroll
        for (int j = 0; j < 4; j++) {
            int lrow = wr * 64 + m * 16 + rg * 4 + j;
            int grow = row0 + lrow;
            float mx = -1e30f;
#pragma unroll
            for (int n = 0; n < 4; n++) {
                float v = acc[m][n][j];
                mx = fmaxf(mx, v);
                int gcol = col0 + wc * 64 + n * 16 + rl;
                if (gcol < NKEYS)
                    scores[(size_t)grow * NKEYS + gcol] = f2bf(v);
            }
#pragma unroll
            for (int sft = 1; sft < 16; sft <<= 1) mx = fmaxf(mx, __shfl_xor(mx, sft));
            if (rl == 0)
                atomicMax(&tmax[lrow], enc16(f2bf(mx)));
        }
    }
    __syncthreads();
    if (tid < BM)
        tilemax[(size_t)(row0 + tid) * NT + g] = (unsigned short)tmax[tid];
}

// ------------------------------------------------- K2: select+refine+output
__global__ __launch_bounds__(256)
void select_kernel(const float* __restrict__ x, const float* __restrict__ keys,
                   const float* __restrict__ vals, const unsigned short* __restrict__ scores,
                   const unsigned short* __restrict__ tilemax, float* __restrict__ out) {
    const int n    = blockIdx.x;
    const int tid  = threadIdx.x;
    const int lane = tid & 63;
    const int w    = tid >> 6;

    __shared__ __align__(16) float qs[DDIM];
    __shared__ unsigned short enc_t[NT];
    __shared__ int    hist[256];
    __shared__ int    tiles[TCAP];
    __shared__ int    cand[CCAP];
    __shared__ double rsc[CCAP];
    __shared__ float  wgt[KTOP];
    __shared__ int    topslot[KTOP];
    __shared__ float  topval[KTOP];
    __shared__ int    ntiles, ncand, sbsel, sabove, st32e;

    reinterpret_cast<f32x4*>(qs)[tid] = reinterpret_cast<const f32x4*>(x + (size_t)n * DDIM)[tid];
    hist[tid] = 0;
    if (tid < 32) { wgt[tid] = 0.f; topslot[tid] = -1; }
    if (tid == 0) { ntiles = 0; ncand = 0; }
    for (int i = tid; i < NT; i += 256)
        enc_t[i] = (i < NCOLT) ? tilemax[(size_t)n * NT + i] : 0;
    __syncthreads();

    // --- exact 32nd-largest tile-max via two-level 8-bit radix ---
    for (int i = tid; i < NT; i += 256) atomicAdd(&hist[enc_t[i] >> 8], 1);
    __syncthreads();
    if (tid == 0) {
        int cum = 0, b = 255;
        for (; b >= 0; b--) { cum += hist[b]; if (cum >= KTOP) break; }
        sbsel = b; sabove = cum - hist[b];
    }
    __syncthreads();
    const int bsel = sbsel;
    hist[tid] = 0;
    __syncthreads();
    for (int i = tid; i < NT; i += 256) {
        int e = enc_t[i];
        if ((e >> 8) == bsel) atomicAdd(&hist[e & 0xFF], 1);
    }
    __syncthreads();
    if (tid == 0) {
        int cum = sabove, lb = 255;
        for (; lb >= 0; lb--) { cum += hist[lb]; if (cum >= KTOP) break; }
        st32e = (bsel << 8) | lb;
    }
    __syncthreads();
    const float thr = dec_enc(st32e) - TMARGIN;

    // --- select tiles with max >= thr ---
    for (int i = tid; i < NT; i += 256) {
        if (dec_enc(enc_t[i]) >= thr) {
            int p = atomicAdd(&ntiles, 1);
            if (p < TCAP) tiles[p] = i;
        }
    }
    __syncthreads();
    const int nt = ntiles < TCAP ? ntiles : TCAP;

    // --- scan selected tiles, collect candidates >= thr ---
    for (int idx = tid; idx < nt * BN; idx += 256) {
        int col = tiles[idx >> 7] * BN + (idx & 127);
        if (col < NKEYS) {
            float v = bf2f(scores[(size_t)n * NKEYS + col]);
            if (v >= thr) {
                int p = atomicAdd(&ncand, 1);
                if (p < CCAP) cand[p] = col;
            }
        }
    }
    __syncthreads();
    const int cnt = ncand < CCAP ? ncand : CCAP;

    // --- refine: exact dot(x_row, keys[cand]) with f64 accum, one wave/cand ---
    for (int ci = w; ci < cnt; ci += 4) {
        const f32x4* kv = reinterpret_cast<const f32x4*>(keys + (size_t)cand[ci] * DDIM) + lane * 4;
        const f32x4* qv = reinterpret_cast<const f32x4*>(qs) + lane * 4;
        double a = 0.0;
#pragma unroll
        for (int i = 0; i < 4; i++) {
            f32x4 q = qv[i], k = kv[i];
            a += (double)q.x * k.x + (double)q.y * k.y + (double)q.z * k.z + (double)q.w * k.w;
        }
#pragma unroll
        for (int sft = 32; sft >= 1; sft >>= 1) a += __shfl_xor(a, sft);
        if (lane == 0) rsc[ci] = a;
    }
    __syncthreads();

    // --- exact top-32 among candidates (wave 0) ---
    if (w == 0) {
        double v0[4]; int id0[4];
#pragma unroll
        for (int sft = 0; sft < 4; sft++) {
            int p = lane + sft * 64;
            if (p < cnt) { v0[sft] = rsc[p]; id0[sft] = p; } else { v0[sft] = -1e300; id0[sft] = -1; }
        }
        for (int k = 0; k < KTOP; k++) {
            double bv = v0[0]; int bi = id0[0];
#pragma unroll
            for (int sft = 1; sft < 4; sft++) if (v0[sft] > bv) { bv = v0[sft]; bi = id0[sft]; }
#pragma unroll
            for (int sft = 32; sft >= 1; sft >>= 1) {
                double ov = __shfl_xor(bv, sft);
                int    oi = __shfl_xor(bi, sft);
                if (ov > bv) { bv = ov; bi = oi; }
            }
            if (lane == 0) { topslot[k] = bi; topval[k] = (float)bv; }
#pragma unroll
            for (int sft = 0; sft < 4; sft++) if (bi >= 0 && id0[sft] == bi) v0[sft] = -1e300;
        }
    }
    __syncthreads();

    // --- softmax over the 32 exact scores ---
    if (tid == 0) {
        float mx = topval[0];
        float sum = 0.f;
        for (int k = 0; k < KTOP; k++) {
            float e = (topslot[k] >= 0) ? expf(topval[k] - mx) : 0.f;
            wgt[k] = e; sum += e;
        }
        float inv = 1.f / sum;
        for (int k = 0; k < KTOP; k++) wgt[k] *= inv;
    }
    __syncthreads();

    // --- output: weighted sum of selected vals rows ---
    f32x4 accv = (f32x4){0.f, 0.f, 0.f, 0.f};
    for (int k = 0; k < KTOP; k++) {
        int sl = topslot[k];
        if (sl >= 0) {
            float wk = wgt[k];
            f32x4 v = reinterpret_cast<const f32x4*>(vals + (size_t)cand[sl] * DDIM)[tid];
            accv.x += wk * v.x; accv.y += wk * v.y; accv.z += wk * v.z; accv.w += wk * v.w;
        }
    }
    reinterpret_cast<f32x4*>(out + (size_t)n * DDIM)[tid] = accv;
}

// ---------------------------------------------------------------- launch
extern "C" void kernel_launch(void* const* d_in, const int* in_sizes, int n_in,
                              void* d_out, int out_size, void* d_ws, size_t ws_size,
                              hipStream_t stream) {
    const float* x    = (const float*)d_in[0];
    const float* keys = (const float*)d_in[1];
    const float* vals = (const float*)d_in[2];
    float* out = (float*)d_out;

    char* ws = (char*)d_ws;
    unsigned short* scores  = (unsigned short*)ws;                         // 204,800,000 B
    unsigned short* xb      = (unsigned short*)(ws + 204800000);           //   1,048,576 B
    unsigned short* tilemax = (unsigned short*)(ws + 204800000 + 1048576); //   1,605,632 B

    cvt_x_kernel<<<512, 256, 0, stream>>>(x, xb);
    score_gemm<<<4 * NT, 256, 0, stream>>>(keys, xb, scores, tilemax);
    select_kernel<<<MROWS, 256, 0, stream>>>(x, keys, vals, scores, tilemax, out);
}

// Round 10
// 632.310 us; speedup vs baseline: 1.5534x; 1.0464x over previous
//
#include <hip/hip_runtime.h>
#include <hip/hip_bf16.h>
#include <stdint.h>

// KVMemoryLayer: scores = x@keys^T (512x200000, K=1024 fp32), top-32/row,
// softmax, weighted gather of vals.
// R10: champion R3 structure + K-PHASE STAGGER. Diagnosis: the 4 row-tile
//     siblings of a col-tile (same XCD, same instant — by swizzle design)
//     issued the SAME 32KB keys slice each step -> MSHR pileup, no L2 hit,
//     every wave waits the aggregate burst drain (80% of step time). Fix:
//     block rt starts its K loop at slice rt*4 (rotated order) -> siblings
//     read different slices; leader fills L2, others hit it 4-12 steps later.
//     Accumulation-order change only perturbs bf16 score rounding (margin
//     0.125 >> 1e-3); final output comes from exact f64 refine -> unchanged.

#define KTOP 32
#define MROWS 512
#define NKEYS 200000
#define DDIM 1024

#define BM 128
#define BN 128
#define BK 64
#define LDT 72          // padded LDS row length in bf16 elems (144 B)
#define NSTEP 16        // DDIM/BK
#define NCOLT 1563      // ceil(200000/128)
#define NT 1568         // padded tile count (multiple of 8 for swizzle)
#define TCAP 256
#define CCAP 256
#define TMARGIN 0.125f  // >> 2*bf16-gemm error (~0.004); provable coverage

typedef __attribute__((ext_vector_type(4))) float f32x4;
typedef __attribute__((ext_vector_type(8))) short short8;

__device__ __forceinline__ unsigned short f2bf(float f) {      // hw RNE cvt
    __hip_bfloat16 h = __float2bfloat16(f);
    return *reinterpret_cast<unsigned short*>(&h);
}
__device__ __forceinline__ int enc16(unsigned short u) {       // monotone order-encode
    return (int)(u ^ ((u & 0x8000u) ? 0xFFFFu : 0x8000u));
}
__device__ __forceinline__ float dec_enc(int e) {              // encoded -> float
    unsigned short u = (unsigned short)((e & 0x8000) ? (e ^ 0x8000) : (e ^ 0xFFFF));
    return __uint_as_float((unsigned int)u << 16);
}
__device__ __forceinline__ float bf2f(unsigned short u) {
    return __uint_as_float((unsigned int)u << 16);
}

// ---------------------------------------------------------------- cvt x->bf16
__global__ void cvt_x_kernel(const float* __restrict__ x, unsigned short* __restrict__ xb) {
    int i = blockIdx.x * blockDim.x + threadIdx.x;      // 131072 threads, 4 elems each
    f32x4 v = reinterpret_cast<const f32x4*>(x)[i];
    ushort4 o;
    o.x = f2bf(v.x); o.y = f2bf(v.y); o.z = f2bf(v.z); o.w = f2bf(v.w);
    reinterpret_cast<ushort4*>(xb)[i] = o;
}

// ---------------------------------------------------------------- K1: scores
__global__ __launch_bounds__(256, 3)
void score_gemm(const float* __restrict__ keys, const unsigned short* __restrict__ xb,
                unsigned short* __restrict__ scores, unsigned short* __restrict__ tilemax) {
    __shared__ unsigned short As[BM * LDT];
    __shared__ unsigned short Bs[BN * LDT];
    __shared__ int tmax[BM];

    const int tid  = threadIdx.x;
    const int lane = tid & 63;
    const int wid  = tid >> 6;
    const int wr   = wid >> 1;          // 2x2 wave grid, 64x64 per wave
    const int wc   = wid & 1;

    // XCD-group swizzle: the 4 row-tile blocks of one col-tile get bids that
    // are congruent mod 8 (same XCD under round-robin) and 8 apart.
    const int bid = blockIdx.x;
    const int s   = bid & 7;
    const int u   = bid >> 3;
    const int rt  = u & 3;
    const int g   = (u >> 2) * 8 + s;   // col tile 0..1567
    if (g >= NCOLT) return;
    const int row0 = rt * BM;
    const int col0 = g * BN;

    // K-phase stagger: sibling rt starts at slice rt*4 (rotated K order).
    const int kbase = rt * 4;
#define KOF(t) ((((t) + kbase) & (NSTEP - 1)) * BK)

    if (tid < BM) tmax[tid] = 0;        // enc 0 < any real finite score's enc

    f32x4 acc[4][4];
#pragma unroll
    for (int m = 0; m < 4; m++)
#pragma unroll
        for (int n = 0; n < 4; n++) acc[m][n] = (f32x4){0.f, 0.f, 0.f, 0.f};

    short8 areg[4];
    f32x4  breg[8];

    auto loadA = [&](int k0) {
#pragma unroll
        for (int i = 0; i < 4; i++) {
            int c = i * 256 + tid;                 // 0..1023  (16B chunks of A tile)
            int r = c >> 3, j = c & 7;
            areg[i] = *reinterpret_cast<const short8*>(xb + (size_t)(row0 + r) * DDIM + k0 + j * 8);
        }
    };
    auto loadB = [&](int k0) {
#pragma unroll
        for (int i = 0; i < 8; i++) {
            int c = i * 256 + tid;                 // 0..2047  (float4 chunks of B tile)
            int r = c >> 4, j = c & 15;
            int gr = col0 + r; gr = (gr < NKEYS) ? gr : (NKEYS - 1);   // clamp OOB cols
            breg[i] = *reinterpret_cast<const f32x4*>(keys + (size_t)gr * DDIM + k0 + j * 4);
        }
    };
    auto writeLDS = [&]() {
#pragma unroll
        for (int i = 0; i < 4; i++) {
            int c = i * 256 + tid;
            int r = c >> 3, j = c & 7;
            *reinterpret_cast<short8*>(&As[r * LDT + j * 8]) = areg[i];
        }
#pragma unroll
        for (int i = 0; i < 8; i++) {
            int c = i * 256 + tid;
            int r = c >> 4, j = c & 15;
            ushort4 o;
            o.x = f2bf(breg[i].x); o.y = f2bf(breg[i].y);
            o.z = f2bf(breg[i].z); o.w = f2bf(breg[i].w);
            *reinterpret_cast<ushort4*>(&Bs[r * LDT + j * 4]) = o;
        }
    };

    const int rl = lane & 15;
    const int kl = (lane >> 4) * 8;

    auto compute = [&]() {
        const unsigned short* Ab = &As[(wr * 64 + rl) * LDT + kl];
        const unsigned short* Bb = &Bs[(wc * 64 + rl) * LDT + kl];
#pragma unroll
        for (int kk = 0; kk < BK; kk += 32) {
            short8 af[4], bf[4];
#pragma unroll
            for (int m = 0; m < 4; m++) af[m] = *reinterpret_cast<const short8*>(Ab + m * 16 * LDT + kk);
#pragma unroll
            for (int n = 0; n < 4; n++) bf[n] = *reinterpret_cast<const short8*>(Bb + n * 16 * LDT + kk);
#pragma unroll
            for (int m = 0; m < 4; m++)
#pragma unroll
                for (int n = 0; n < 4; n++)
                    acc[m][n] = __builtin_amdgcn_mfma_f32_16x16x32_bf16(af[m], bf[n], acc[m][n], 0, 0, 0);
        }
    };

    loadA(KOF(0)); loadB(KOF(0));
    for (int t = 0; t < NSTEP; t++) {
        __syncthreads();                 // previous compute done; LDS reusable
        writeLDS();
        __syncthreads();
        if (t + 1 < NSTEP) { loadA(KOF(t + 1)); loadB(KOF(t + 1)); }  // overlap w/ MFMA
        compute();
    }

    // epilogue: store bf16 scores (predicated) + per-(row,tile) max
    const int rg = lane >> 4;
#pragma unroll
    for (int m = 0; m < 4; m++) {
#pragma unroll
        for (int j = 0; j < 4; j++) {
            int lrow = wr * 64 + m * 16 + rg * 4 + j;
            int grow = row0 + lrow;
            float mx = -1e30f;
#pragma unroll
            for (int n = 0; n < 4; n++) {
                float v = acc[m][n][j];
                mx = fmaxf(mx, v);      // OOB lanes duplicate key NKEYS-1 (valid, in-tile)
                int gcol = col0 + wc * 64 + n * 16 + rl;
                if (gcol < NKEYS)
                    scores[(size_t)grow * NKEYS + gcol] = f2bf(v);
            }
#pragma unroll
            for (int sft = 1; sft < 16; sft <<= 1) mx = fmaxf(mx, __shfl_xor(mx, sft));
            if (rl == 0)
                atomicMax(&tmax[lrow], enc16(f2bf(mx)));
        }
    }
    __syncthreads();
    if (tid < BM)
        tilemax[(size_t)(row0 + tid) * NT + g] = (unsigned short)tmax[tid];
#undef KOF
}

// ------------------------------------------------- K2: select+refine+output
__global__ __launch_bounds__(256)
void select_kernel(const float* __restrict__ x, const float* __restrict__ keys,
                   const float* __restrict__ vals, const unsigned short* __restrict__ scores,
                   const unsigned short* __restrict__ tilemax, float* __restrict__ out) {
    const int n    = blockIdx.x;
    const int tid  = threadIdx.x;
    const int lane = tid & 63;
    const int w    = tid >> 6;

    __shared__ __align__(16) float qs[DDIM];
    __shared__ unsigned short enc_t[NT];
    __shared__ int    hist[256];
    __shared__ int    tiles[TCAP];
    __shared__ int    cand[CCAP];
    __shared__ double rsc[CCAP];
    __shared__ float  wgt[KTOP];
    __shared__ int    topslot[KTOP];
    __shared__ float  topval[KTOP];
    __shared__ int    ntiles, ncand, sbsel, sabove, st32e;

    reinterpret_cast<f32x4*>(qs)[tid] = reinterpret_cast<const f32x4*>(x + (size_t)n * DDIM)[tid];
    hist[tid] = 0;
    if (tid < 32) { wgt[tid] = 0.f; topslot[tid] = -1; }
    if (tid == 0) { ntiles = 0; ncand = 0; }
    // load tile-max row (encoded bf16); phantom tiles (>=NCOLT) forced to 0
    for (int i = tid; i < NT; i += 256)
        enc_t[i] = (i < NCOLT) ? tilemax[(size_t)n * NT + i] : 0;
    __syncthreads();

    // --- exact 32nd-largest tile-max via two-level 8-bit radix ---
    for (int i = tid; i < NT; i += 256) atomicAdd(&hist[enc_t[i] >> 8], 1);
    __syncthreads();
    if (tid == 0) {
        int cum = 0, b = 255;
        for (; b >= 0; b--) { cum += hist[b]; if (cum >= KTOP) break; }
        sbsel = b; sabove = cum - hist[b];
    }
    __syncthreads();
    const int bsel = sbsel;
    hist[tid] = 0;
    __syncthreads();
    for (int i = tid; i < NT; i += 256) {
        int e = enc_t[i];
        if ((e >> 8) == bsel) atomicAdd(&hist[e & 0xFF], 1);
    }
    __syncthreads();
    if (tid == 0) {
        int cum = sabove, lb = 255;
        for (; lb >= 0; lb--) { cum += hist[lb]; if (cum >= KTOP) break; }
        st32e = (bsel << 8) | lb;
    }
    __syncthreads();
    const float thr = dec_enc(st32e) - TMARGIN;

    // --- select tiles with max >= thr ---
    for (int i = tid; i < NT; i += 256) {
        if (dec_enc(enc_t[i]) >= thr) {
            int p = atomicAdd(&ntiles, 1);
            if (p < TCAP) tiles[p] = i;
        }
    }
    __syncthreads();
    const int nt = ntiles < TCAP ? ntiles : TCAP;

    // --- scan selected tiles, collect candidates >= thr ---
    for (int idx = tid; idx < nt * BN; idx += 256) {
        int col = tiles[idx >> 7] * BN + (idx & 127);
        if (col < NKEYS) {
            float v = bf2f(scores[(size_t)n * NKEYS + col]);
            if (v >= thr) {
                int p = atomicAdd(&ncand, 1);
                if (p < CCAP) cand[p] = col;
            }
        }
    }
    __syncthreads();
    const int cnt = ncand < CCAP ? ncand : CCAP;

    // --- refine: exact dot(x_row, keys[cand]) with f64 accum, one wave/cand ---
    for (int ci = w; ci < cnt; ci += 4) {
        const f32x4* kv = reinterpret_cast<const f32x4*>(keys + (size_t)cand[ci] * DDIM) + lane * 4;
        const f32x4* qv = reinterpret_cast<const f32x4*>(qs) + lane * 4;
        double a = 0.0;
#pragma unroll
        for (int i = 0; i < 4; i++) {
            f32x4 q = qv[i], k = kv[i];
            a += (double)q.x * k.x + (double)q.y * k.y + (double)q.z * k.z + (double)q.w * k.w;
        }
#pragma unroll
        for (int sft = 32; sft >= 1; sft >>= 1) a += __shfl_xor(a, sft);
        if (lane == 0) rsc[ci] = a;
    }
    __syncthreads();

    // --- exact top-32 among candidates (wave 0) ---
    if (w == 0) {
        double v0[4]; int id0[4];
#pragma unroll
        for (int sft = 0; sft < 4; sft++) {
            int p = lane + sft * 64;
            if (p < cnt) { v0[sft] = rsc[p]; id0[sft] = p; } else { v0[sft] = -1e300; id0[sft] = -1; }
        }
        for (int k = 0; k < KTOP; k++) {
            double bv = v0[0]; int bi = id0[0];
#pragma unroll
            for (int sft = 1; sft < 4; sft++) if (v0[sft] > bv) { bv = v0[sft]; bi = id0[sft]; }
#pragma unroll
            for (int sft = 32; sft >= 1; sft >>= 1) {
                double ov = __shfl_xor(bv, sft);
                int    oi = __shfl_xor(bi, sft);
                if (ov > bv) { bv = ov; bi = oi; }
            }
            if (lane == 0) { topslot[k] = bi; topval[k] = (float)bv; }
#pragma unroll
            for (int sft = 0; sft < 4; sft++) if (bi >= 0 && id0[sft] == bi) v0[sft] = -1e300;
        }
    }
    __syncthreads();

    // --- softmax over the 32 exact scores ---
    if (tid == 0) {
        float mx = topval[0];
        float sum = 0.f;
        for (int k = 0; k < KTOP; k++) {
            float e = (topslot[k] >= 0) ? expf(topval[k] - mx) : 0.f;
            wgt[k] = e; sum += e;
        }
        float inv = 1.f / sum;
        for (int k = 0; k < KTOP; k++) wgt[k] *= inv;
    }
    __syncthreads();

    // --- output: weighted sum of selected vals rows ---
    f32x4 accv = (f32x4){0.f, 0.f, 0.f, 0.f};
    for (int k = 0; k < KTOP; k++) {
        int sl = topslot[k];
        if (sl >= 0) {
            float wk = wgt[k];
            f32x4 v = reinterpret_cast<const f32x4*>(vals + (size_t)cand[sl] * DDIM)[tid];
            accv.x += wk * v.x; accv.y += wk * v.y; accv.z += wk * v.z; accv.w += wk * v.w;
        }
    }
    reinterpret_cast<f32x4*>(out + (size_t)n * DDIM)[tid] = accv;
}

// ---------------------------------------------------------------- launch
extern "C" void kernel_launch(void* const* d_in, const int* in_sizes, int n_in,
                              void* d_out, int out_size, void* d_ws, size_t ws_size,
                              hipStream_t stream) {
    const float* x    = (const float*)d_in[0];
    const float* keys = (const float*)d_in[1];
    const float* vals = (const float*)d_in[2];
    float* out = (float*)d_out;

    char* ws = (char*)d_ws;
    unsigned short* scores  = (unsigned short*)ws;                         // 204,800,000 B
    unsigned short* xb      = (unsigned short*)(ws + 204800000);           //   1,048,576 B
    unsigned short* tilemax = (unsigned short*)(ws + 204800000 + 1048576); //   1,605,632 B

    cvt_x_kernel<<<512, 256, 0, stream>>>(x, xb);
    score_gemm<<<4 * NT, 256, 0, stream>>>(keys, xb, scores, tilemax);
    select_kernel<<<MROWS, 256, 0, stream>>>(x, keys, vals, scores, tilemax, out);
}

// Round 11
// 563.451 us; speedup vs baseline: 1.7433x; 1.1222x over previous
//
#include <hip/hip_runtime.h>
#include <hip/hip_bf16.h>
#include <stdint.h>

// KVMemoryLayer: scores = x@keys^T (512x200000, K=1024 fp32), top-32/row,
// softmax, weighted gather of vals.
// R11: BM=512 — each block computes ALL 512 rows x 64 cols, so every keys
//     byte is read exactly ONCE from HBM (was 2x: FETCH 1.7GB -> ~0.85GB).
//     grid=3125 (200000=64*3125, no OOB), 1024 thr / 16 waves, wave tile
//     32x64 -> acc only 32 regs; staging 20 regs -> fits (1024,4)'s 128
//     budget with margin (R7 spilled at demand ~160; here ~110).
//     A (xb, 1MB) is L3-resident; no XCD swizzle needed. K2 tilemax is now
//     64-wide (NT=3136), same radix/margin selection.

#define KTOP 32
#define MROWS 512
#define NKEYS 200000
#define DDIM 1024

#define BN2 64
#define BK 64
#define LDT 72          // padded LDS row length in bf16 elems (144 B)
#define NSTEP 16        // DDIM/BK
#define NCOLT2 3125     // 200000/64 exactly
#define NT2 3136        // padded (mult of 8, uint4-clean)
#define TCAP 512
#define CCAP 256
#define TMARGIN 0.125f  // >> 2*bf16-gemm error (~0.004); provable coverage

typedef __attribute__((ext_vector_type(4))) float f32x4;
typedef __attribute__((ext_vector_type(8))) short short8;

__device__ __forceinline__ unsigned short f2bf(float f) {      // hw RNE cvt
    __hip_bfloat16 h = __float2bfloat16(f);
    return *reinterpret_cast<unsigned short*>(&h);
}
__device__ __forceinline__ int enc16(unsigned short u) {       // monotone order-encode
    return (int)(u ^ ((u & 0x8000u) ? 0xFFFFu : 0x8000u));
}
__device__ __forceinline__ float dec_enc(int e) {              // encoded -> float
    unsigned short u = (unsigned short)((e & 0x8000) ? (e ^ 0x8000) : (e ^ 0xFFFF));
    return __uint_as_float((unsigned int)u << 16);
}
__device__ __forceinline__ float bf2f(unsigned short u) {
    return __uint_as_float((unsigned int)u << 16);
}

// ---------------------------------------------------------------- cvt x->bf16
__global__ void cvt_x_kernel(const float* __restrict__ x, unsigned short* __restrict__ xb) {
    int i = blockIdx.x * blockDim.x + threadIdx.x;      // 131072 threads, 4 elems each
    f32x4 v = reinterpret_cast<const f32x4*>(x)[i];
    ushort4 o;
    o.x = f2bf(v.x); o.y = f2bf(v.y); o.z = f2bf(v.z); o.w = f2bf(v.w);
    reinterpret_cast<ushort4*>(xb)[i] = o;
}

// ---------------------------------------------------------------- K1: scores
// 1024 threads = 16 waves; wave w owns rows [w*32, w*32+32) x all 64 cols.
__global__ __launch_bounds__(1024, 4)
void score_gemm(const float* __restrict__ keys, const unsigned short* __restrict__ xb,
                unsigned short* __restrict__ scores, unsigned short* __restrict__ tilemax) {
    __shared__ unsigned short As[MROWS * LDT];   // 73728 B
    __shared__ unsigned short Bs[BN2 * LDT];     //  9216 B
    __shared__ int tmax[MROWS];                  //  2048 B

    const int tid  = threadIdx.x;
    const int lane = tid & 63;
    const int w    = tid >> 6;          // wave 0..15

    const int g    = blockIdx.x;        // col tile 0..3124
    const int col0 = g * BN2;

    if (tid < MROWS) tmax[tid] = 0;     // enc 0 < any real finite score's enc

    f32x4 acc[2][4];                    // 32 regs/lane
#pragma unroll
    for (int m = 0; m < 2; m++)
#pragma unroll
        for (int n = 0; n < 4; n++) acc[m][n] = (f32x4){0.f, 0.f, 0.f, 0.f};

    short8 areg[4];                     // 16 regs
    f32x4  breg;                        //  4 regs

    auto loadA = [&](int k0) {
#pragma unroll
        for (int i = 0; i < 4; i++) {
            int c = i * 1024 + tid;                // 0..4095 (16B chunks: 512 rows x 8)
            int r = c >> 3, j = c & 7;
            areg[i] = *reinterpret_cast<const short8*>(xb + (size_t)r * DDIM + k0 + j * 8);
        }
    };
    auto loadB = [&](int k0) {
        int r = tid >> 4, j = tid & 15;            // 64 rows x 16 f32x4-chunks
        breg = *reinterpret_cast<const f32x4*>(keys + (size_t)(col0 + r) * DDIM + k0 + j * 4);
    };
    auto writeLDS = [&]() {
#pragma unroll
        for (int i = 0; i < 4; i++) {
            int c = i * 1024 + tid;
            int r = c >> 3, j = c & 7;
            *reinterpret_cast<short8*>(&As[r * LDT + j * 8]) = areg[i];
        }
        {
            int r = tid >> 4, j = tid & 15;
            ushort4 o;
            o.x = f2bf(breg.x); o.y = f2bf(breg.y);
            o.z = f2bf(breg.z); o.w = f2bf(breg.w);
            *reinterpret_cast<ushort4*>(&Bs[r * LDT + j * 4]) = o;
        }
    };

    const int rl = lane & 15;
    const int kl = (lane >> 4) * 8;

    auto compute = [&]() {
        const unsigned short* Ab = &As[(w * 32 + rl) * LDT + kl];
        const unsigned short* Bb = &Bs[rl * LDT + kl];
#pragma unroll
        for (int kk = 0; kk < BK; kk += 32) {
            short8 af[2], bf[4];
#pragma unroll
            for (int m = 0; m < 2; m++) af[m] = *reinterpret_cast<const short8*>(Ab + m * 16 * LDT + kk);
#pragma unroll
            for (int n = 0; n < 4; n++) bf[n] = *reinterpret_cast<const short8*>(Bb + n * 16 * LDT + kk);
#pragma unroll
            for (int m = 0; m < 2; m++)
#pragma unroll
                for (int n = 0; n < 4; n++)
                    acc[m][n] = __builtin_amdgcn_mfma_f32_16x16x32_bf16(af[m], bf[n], acc[m][n], 0, 0, 0);
        }
    };

    loadA(0); loadB(0);
    for (int t = 0; t < NSTEP; t++) {
        __syncthreads();                 // previous compute done; LDS reusable
        writeLDS();
        __syncthreads();
        if (t + 1 < NSTEP) { loadA((t + 1) * BK); loadB((t + 1) * BK); }  // overlap w/ MFMA
        compute();
    }

    // epilogue: store bf16 scores + per-(row,tile) max (no OOB: 200000=64*3125)
    const int rg = lane >> 4;
#pragma unroll
    for (int m = 0; m < 2; m++) {
#pragma unroll
        for (int j = 0; j < 4; j++) {
            int lrow = w * 32 + m * 16 + rg * 4 + j;
            float mx = -1e30f;
#pragma unroll
            for (int n = 0; n < 4; n++) {
                float v = acc[m][n][j];
                mx = fmaxf(mx, v);
                scores[(size_t)lrow * NKEYS + col0 + n * 16 + rl] = f2bf(v);
            }
#pragma unroll
            for (int sft = 1; sft < 16; sft <<= 1) mx = fmaxf(mx, __shfl_xor(mx, sft));
            if (rl == 0)
                atomicMax(&tmax[lrow], enc16(f2bf(mx)));
        }
    }
    __syncthreads();
    if (tid < MROWS)
        tilemax[(size_t)tid * NT2 + g] = (unsigned short)tmax[tid];
}

// ------------------------------------------------- K2: select+refine+output
__global__ __launch_bounds__(256)
void select_kernel(const float* __restrict__ x, const float* __restrict__ keys,
                   const float* __restrict__ vals, const unsigned short* __restrict__ scores,
                   const unsigned short* __restrict__ tilemax, float* __restrict__ out) {
    const int n    = blockIdx.x;
    const int tid  = threadIdx.x;
    const int lane = tid & 63;
    const int w    = tid >> 6;

    __shared__ __align__(16) float qs[DDIM];
    __shared__ unsigned short enc_t[NT2];
    __shared__ int    hist[256];
    __shared__ int    tiles[TCAP];
    __shared__ int    cand[CCAP];
    __shared__ double rsc[CCAP];
    __shared__ float  wgt[KTOP];
    __shared__ int    topslot[KTOP];
    __shared__ float  topval[KTOP];
    __shared__ int    ntiles, ncand, sbsel, sabove, st32e;

    reinterpret_cast<f32x4*>(qs)[tid] = reinterpret_cast<const f32x4*>(x + (size_t)n * DDIM)[tid];
    hist[tid] = 0;
    if (tid < 32) { wgt[tid] = 0.f; topslot[tid] = -1; }
    if (tid == 0) { ntiles = 0; ncand = 0; }
    // load tile-max row (encoded bf16); phantom tiles (>=NCOLT2) forced to 0
    for (int i = tid; i < NT2; i += 256)
        enc_t[i] = (i < NCOLT2) ? tilemax[(size_t)n * NT2 + i] : 0;
    __syncthreads();

    // --- exact 32nd-largest tile-max via two-level 8-bit radix ---
    for (int i = tid; i < NT2; i += 256) atomicAdd(&hist[enc_t[i] >> 8], 1);
    __syncthreads();
    if (tid == 0) {
        int cum = 0, b = 255;
        for (; b >= 0; b--) { cum += hist[b]; if (cum >= KTOP) break; }
        sbsel = b; sabove = cum - hist[b];
    }
    __syncthreads();
    const int bsel = sbsel;
    hist[tid] = 0;
    __syncthreads();
    for (int i = tid; i < NT2; i += 256) {
        int e = enc_t[i];
        if ((e >> 8) == bsel) atomicAdd(&hist[e & 0xFF], 1);
    }
    __syncthreads();
    if (tid == 0) {
        int cum = sabove, lb = 255;
        for (; lb >= 0; lb--) { cum += hist[lb]; if (cum >= KTOP) break; }
        st32e = (bsel << 8) | lb;
    }
    __syncthreads();
    const float thr = dec_enc(st32e) - TMARGIN;   // covers exact top-32

    // --- select tiles with max >= thr ---
    for (int i = tid; i < NT2; i += 256) {
        if (dec_enc(enc_t[i]) >= thr) {
            int p = atomicAdd(&ntiles, 1);
            if (p < TCAP) tiles[p] = i;
        }
    }
    __syncthreads();
    const int nt = ntiles < TCAP ? ntiles : TCAP;

    // --- scan selected tiles (64 cols each), collect candidates >= thr ---
    for (int idx = tid; idx < nt * BN2; idx += 256) {
        int col = tiles[idx >> 6] * BN2 + (idx & 63);
        float v = bf2f(scores[(size_t)n * NKEYS + col]);
        if (v >= thr) {
            int p = atomicAdd(&ncand, 1);
            if (p < CCAP) cand[p] = col;
        }
    }
    __syncthreads();
    const int cnt = ncand < CCAP ? ncand : CCAP;

    // --- refine: exact dot(x_row, keys[cand]) with f64 accum, one wave/cand ---
    for (int ci = w; ci < cnt; ci += 4) {
        const f32x4* kv = reinterpret_cast<const f32x4*>(keys + (size_t)cand[ci] * DDIM) + lane * 4;
        const f32x4* qv = reinterpret_cast<const f32x4*>(qs) + lane * 4;
        double a = 0.0;
#pragma unroll
        for (int i = 0; i < 4; i++) {
            f32x4 q = qv[i], k = kv[i];
            a += (double)q.x * k.x + (double)q.y * k.y + (double)q.z * k.z + (double)q.w * k.w;
        }
#pragma unroll
        for (int sft = 32; sft >= 1; sft >>= 1) a += __shfl_xor(a, sft);
        if (lane == 0) rsc[ci] = a;
    }
    __syncthreads();

    // --- exact top-32 among candidates (wave 0) ---
    if (w == 0) {
        double v0[4]; int id0[4];
#pragma unroll
        for (int sft = 0; sft < 4; sft++) {
            int p = lane + sft * 64;
            if (p < cnt) { v0[sft] = rsc[p]; id0[sft] = p; } else { v0[sft] = -1e300; id0[sft] = -1; }
        }
        for (int k = 0; k < KTOP; k++) {
            double bv = v0[0]; int bi = id0[0];
#pragma unroll
            for (int sft = 1; sft < 4; sft++) if (v0[sft] > bv) { bv = v0[sft]; bi = id0[sft]; }
#pragma unroll
            for (int sft = 32; sft >= 1; sft >>= 1) {
                double ov = __shfl_xor(bv, sft);
                int    oi = __shfl_xor(bi, sft);
                if (ov > bv) { bv = ov; bi = oi; }
            }
            if (lane == 0) { topslot[k] = bi; topval[k] = (float)bv; }
#pragma unroll
            for (int sft = 0; sft < 4; sft++) if (bi >= 0 && id0[sft] == bi) v0[sft] = -1e300;
        }
    }
    __syncthreads();

    // --- softmax over the 32 exact scores ---
    if (tid == 0) {
        float mx = topval[0];
        float sum = 0.f;
        for (int k = 0; k < KTOP; k++) {
            float e = (topslot[k] >= 0) ? expf(topval[k] - mx) : 0.f;
            wgt[k] = e; sum += e;
        }
        float inv = 1.f / sum;
        for (int k = 0; k < KTOP; k++) wgt[k] *= inv;
    }
    __syncthreads();

    // --- output: weighted sum of selected vals rows ---
    f32x4 accv = (f32x4){0.f, 0.f, 0.f, 0.f};
    for (int k = 0; k < KTOP; k++) {
        int sl = topslot[k];
        if (sl >= 0) {
            float wk = wgt[k];
            f32x4 v = reinterpret_cast<const f32x4*>(vals + (size_t)cand[sl] * DDIM)[tid];
            accv.x += wk * v.x; accv.y += wk * v.y; accv.z += wk * v.z; accv.w += wk * v.w;
        }
    }
    reinterpret_cast<f32x4*>(out + (size_t)n * DDIM)[tid] = accv;
}

// ---------------------------------------------------------------- launch
extern "C" void kernel_launch(void* const* d_in, const int* in_sizes, int n_in,
                              void* d_out, int out_size, void* d_ws, size_t ws_size,
                              hipStream_t stream) {
    const float* x    = (const float*)d_in[0];
    const float* keys = (const float*)d_in[1];
    const float* vals = (const float*)d_in[2];
    float* out = (float*)d_out;

    char* ws = (char*)d_ws;
    unsigned short* scores  = (unsigned short*)ws;                         // 204,800,000 B
    unsigned short* xb      = (unsigned short*)(ws + 204800000);           //   1,048,576 B
    unsigned short* tilemax = (unsigned short*)(ws + 204800000 + 1048576); //   3,211,264 B

    cvt_x_kernel<<<512, 256, 0, stream>>>(x, xb);
    score_gemm<<<NCOLT2, 1024, 0, stream>>>(keys, xb, scores, tilemax);
    select_kernel<<<MROWS, 256, 0, stream>>>(x, keys, vals, scores, tilemax, out);
}